// Round 4
// baseline (198.432 us; speedup 1.0000x reference)
//
#include <hip/hip_runtime.h>
#include <hip/hip_bf16.h>

typedef __attribute__((ext_vector_type(8))) short short8;
typedef __attribute__((ext_vector_type(4))) float floatx4;
typedef unsigned int u32;

#define NN 4096

static __device__ __forceinline__ unsigned f2bf_rne(float x) {
    union { float f; unsigned u; } v; v.f = x;
    unsigned r = v.u + 0x7fffu + ((v.u >> 16) & 1u);
    return r >> 16;
}
static __device__ __forceinline__ float bf2f(unsigned hi) {
    union { unsigned u; float f; } v; v.u = hi << 16; return v.f;
}

// ---- wc: ONE block computes Wc^T = (W1@W2)^T [64 n][68 k] f32 and
// w1a = {W1@aL, W1@aR} into workspace.
__global__ __launch_bounds__(256, 1)
void wc_kernel(const float* __restrict__ W1,
               const float* __restrict__ W2,
               const float* __restrict__ alpha,
               float* __restrict__ WcstG,
               float* __restrict__ w1aG) {
    __shared__ __align__(16) float W1s[64 * 68];
    __shared__ __align__(16) float W2s[64 * 68];
    __shared__ float als[128];
    const int t = threadIdx.x;
    #pragma unroll
    for (int s = 0; s < 4; ++s) {
        int idx = s * 1024 + t * 4;
        int r = idx >> 6, cc = idx & 63;
        *(float4*)&W1s[r * 68 + cc] = *(const float4*)(W1 + idx);
        *(float4*)&W2s[r * 68 + cc] = *(const float4*)(W2 + idx);
    }
    if (t < 128) als[t] = alpha[t];
    __syncthreads();
    const int k = t >> 2, nq = t & 3;
    float acc[16];
    #pragma unroll
    for (int i = 0; i < 16; ++i) acc[i] = 0.f;
    for (int mm = 0; mm < 64; ++mm) {
        float w1v = W1s[k * 68 + mm];
        #pragma unroll
        for (int i = 0; i < 16; ++i)
            acc[i] += w1v * W2s[mm * 68 + nq * 16 + i];
    }
    #pragma unroll
    for (int i = 0; i < 16; ++i)
        WcstG[(nq * 16 + i) * 68 + k] = acc[i];
    if (t < 64) {
        float sl = 0.f, sr = 0.f;
        for (int cc2 = 0; cc2 < 64; ++cc2) {
            float wv = W1s[t * 68 + cc2];
            sl += wv * als[cc2];
            sr += wv * als[64 + cc2];
        }
        w1aG[t] = sl; w1aG[64 + t] = sr;
    }
}

// ---- prep: G = X@Wc (bf16 hi/lo MFMA) -> Gt bf16 [b*64+c][4096]; lv/rv fp32.
__global__ __launch_bounds__(256, 4)
void prep_kernel(const float* __restrict__ X,
                 const float* __restrict__ WcstG,
                 const float* __restrict__ w1aG,
                 unsigned short* __restrict__ Gt,
                 float* __restrict__ lv,
                 float* __restrict__ rv) {
    __shared__ __align__(16) char sm[17920];
    float* Wcst = (float*)sm;                 // [64 n][68 k]
    float* w1s  = (float*)(sm + 17408);       // [128]
    float* GsT  = (float*)sm;                 // epilogue reuse: [64][68]

    const int t = threadIdx.x;
    const int row0 = blockIdx.x * 64;         // flat b*N + n
    const int b = row0 >> 12, n0 = row0 & (NN - 1);
    const int w = t >> 6, lane = t & 63;
    const int m = lane & 15, q = lane >> 4;

    const int row = row0 + w * 16 + m;
    const float* xp = X + (size_t)row * 64;
    float4 x0 = *(const float4*)(xp + q * 8);
    float4 x1 = *(const float4*)(xp + q * 8 + 4);
    float4 x2 = *(const float4*)(xp + 32 + q * 8);
    float4 x3 = *(const float4*)(xp + 32 + q * 8 + 4);

    #pragma unroll
    for (int it = 0; it < 5; ++it) {
        int i = it * 1024 + t * 4;
        if (i < 4352) *(float4*)&Wcst[i] = *(const float4*)(WcstG + i);
    }
    if (t < 128) w1s[t] = w1aG[t];
    __syncthreads();

    const float xs[16] = {x0.x,x0.y,x0.z,x0.w, x1.x,x1.y,x1.z,x1.w,
                          x2.x,x2.y,x2.z,x2.w, x3.x,x3.y,x3.z,x3.w};

    float pl = 0.f, pr = 0.f;
    #pragma unroll
    for (int ks = 0; ks < 2; ++ks)
        #pragma unroll
        for (int j = 0; j < 8; ++j) {
            int k = ks * 32 + q * 8 + j;
            float xv = xs[ks * 8 + j];
            pl += xv * w1s[k];
            pr += xv * w1s[64 + k];
        }
    pl += __shfl_xor(pl, 16, 64); pl += __shfl_xor(pl, 32, 64);
    pr += __shfl_xor(pr, 16, 64); pr += __shfl_xor(pr, 32, 64);
    if (q == 0) { lv[row] = pl; rv[row] = pr; }

    short8 ah[2], al[2];
    #pragma unroll
    for (int ks = 0; ks < 2; ++ks)
        #pragma unroll
        for (int j = 0; j < 8; ++j) {
            float f = xs[ks * 8 + j];
            unsigned hb = f2bf_rne(f);
            float res = f - bf2f(hb);
            ah[ks][j] = (short)hb;
            al[ks][j] = (short)f2bf_rne(res);
        }

    short8 bfr[4][2];
    #pragma unroll
    for (int nt = 0; nt < 4; ++nt)
        #pragma unroll
        for (int ks = 0; ks < 2; ++ks) {
            const float* wp = &Wcst[(nt * 16 + m) * 68 + ks * 32 + q * 8];
            float4 w0 = *(const float4*)wp;
            float4 w1 = *(const float4*)(wp + 4);
            short8 bf;
            bf[0] = (short)f2bf_rne(w0.x); bf[1] = (short)f2bf_rne(w0.y);
            bf[2] = (short)f2bf_rne(w0.z); bf[3] = (short)f2bf_rne(w0.w);
            bf[4] = (short)f2bf_rne(w1.x); bf[5] = (short)f2bf_rne(w1.y);
            bf[6] = (short)f2bf_rne(w1.z); bf[7] = (short)f2bf_rne(w1.w);
            bfr[nt][ks] = bf;
        }

    floatx4 acc[4] = {{0,0,0,0},{0,0,0,0},{0,0,0,0},{0,0,0,0}};
    #pragma unroll
    for (int ks = 0; ks < 2; ++ks)
        #pragma unroll
        for (int nt = 0; nt < 4; ++nt) {
            acc[nt] = __builtin_amdgcn_mfma_f32_16x16x32_bf16(ah[ks], bfr[nt][ks], acc[nt], 0, 0, 0);
            acc[nt] = __builtin_amdgcn_mfma_f32_16x16x32_bf16(al[ks], bfr[nt][ks], acc[nt], 0, 0, 0);
        }

    __syncthreads();
    #pragma unroll
    for (int nt = 0; nt < 4; ++nt)
        #pragma unroll
        for (int rg = 0; rg < 4; ++rg)
            GsT[(nt * 16 + m) * 68 + w * 16 + q * 4 + rg] = acc[nt][rg];
    __syncthreads();
    unsigned* Gu = (unsigned*)Gt;
    #pragma unroll
    for (int it2 = 0; it2 < 8; ++it2) {
        int c2 = (t >> 5) + it2 * 8;
        int np = t & 31;
        unsigned lo = f2bf_rne(GsT[c2 * 68 + 2 * np]);
        unsigned hi = f2bf_rne(GsT[c2 * 68 + 2 * np + 1]);
        Gu[(((((size_t)(b * 64 + c2)) << 12) + n0) >> 1) + np] = lo | (hi << 16);
    }
}

// ---- attn v4: ZERO barriers in the main loop. Each lane loads its MFMA
// B-fragment DIRECTLY from Gt (16 contiguous bytes = dwordx4, already in
// B-frag layout: lane(m,q) reads channel c0+m, j = grp*1024+cc*32+q*8).
// No LDS staging of G, no DMA, no cross-wave sharing -> waves slip freely
// and the SIMD hides global latency with 4 independent waves. The 4 waves
// of a group issue identical B-loads (L1 broadcast); Gt is L2-resident.
// rv staged once into LDS (rs). Depth-2 named-register prefetch (even/odd
// sets) for A and B frags. LDS reused for the epilogue reduction only.
__global__ __launch_bounds__(1024, 4)
void attn_kernel(const float* __restrict__ A,
                 const unsigned short* __restrict__ Gt,
                 const float* __restrict__ lv,
                 const float* __restrict__ rv,
                 float* __restrict__ out) {
    __shared__ __align__(16) char sm[34816];   // rs[4096] f32; epilogue red[2][64][68]
    float* rs = (float*)sm;

    const int bx = blockIdx.x;
    const int i0 = (bx & 63) * 64;
    const int b  = bx >> 6;
    const int t = threadIdx.x;
    const int wave = t >> 6, lane = t & 63;
    const int grp = wave >> 2, wsub = wave & 3;
    const int m = lane & 15, q = lane >> 4;
    const int irow = wsub * 16 + m;

    // one-time rv stage
    *(float4*)&rs[t * 4] = *(const float4*)(rv + (size_t)b * NN + t * 4);

    const float* aRow = A + (size_t)(i0 + irow) * NN + grp * 1024 + q * 8;
    // B-frag channel-block base pointers (c0 = 0,16,32,48; channel = c0+m)
    const unsigned short* gB0 = Gt + (((size_t)(b * 64 + m)) << 12) + grp * 1024 + q * 8;
    const unsigned short* gB1 = gB0 + ((size_t)16 << 12);
    const unsigned short* gB2 = gB0 + ((size_t)32 << 12);
    const unsigned short* gB3 = gB0 + ((size_t)48 << 12);

    const float li = lv[b * NN + i0 + irow] * 1.44269504f;   // fold log2e
    const float li001 = li * 0.01f;

    // depth-2 prefetch: chunk 0 -> set A, chunk 1 -> set B
    float4 a0A = *(const float4*)(aRow);
    float4 a1A = *(const float4*)(aRow + 4);
    short8 b0A = *(const short8*)(gB0);
    short8 b1A = *(const short8*)(gB1);
    short8 b2A = *(const short8*)(gB2);
    short8 b3A = *(const short8*)(gB3);
    float4 a0B = *(const float4*)(aRow + 32);
    float4 a1B = *(const float4*)(aRow + 36);
    short8 b0B = *(const short8*)(gB0 + 32);
    short8 b1B = *(const short8*)(gB1 + 32);
    short8 b2B = *(const short8*)(gB2 + 32);
    short8 b3B = *(const short8*)(gB3 + 32);

    const bool diag_grp = ((i0 >> 10) == grp);
    const int jd = (i0 + irow) - grp * 1024;

    floatx4 acc0 = {0,0,0,0}, acc1 = {0,0,0,0}, acc2 = {0,0,0,0}, acc3 = {0,0,0,0};
    float dsum = 0.f;

    __syncthreads();            // rs ready (only barrier before epilogue)

    auto genE = [&](float4 a0, float4 a1, int chunk) -> short8 {
        float aa[8] = {a0.x, a0.y, a0.z, a0.w, a1.x, a1.y, a1.z, a1.w};
        if (diag_grp && ((jd >> 5) == chunk)) {            // adj diag := 1
            const int dd = jd - (chunk * 32 + q * 8);
            #pragma unroll
            for (int e = 0; e < 8; ++e) if (dd == e) aa[e] = 1.0f;
        }
        const float4 r0 = *(const float4*)&rs[grp * 1024 + chunk * 32 + q * 8];
        const float4 r1 = *(const float4*)&rs[grp * 1024 + chunk * 32 + q * 8 + 4];
        const float rr[8] = {r0.x, r0.y, r0.z, r0.w, r1.x, r1.y, r1.z, r1.w};
        unsigned up[8];
        #pragma unroll
        for (int e = 0; e < 8; ++e) {
            float s = fmaxf(li * rr[e], li001 * rr[e]);    // leaky(li*r)
            float ev = __builtin_amdgcn_exp2f(s) * aa[e];
            unsigned u = __float_as_uint(ev) + 0x8000u;
            up[e] = u;
            dsum += __uint_as_float(u & 0xffff0000u);      // den = same bf16 vals
        }
        union { unsigned u[4]; short8 s8; } cv;
        cv.u[0] = __builtin_amdgcn_perm(up[1], up[0], 0x07060302u);
        cv.u[1] = __builtin_amdgcn_perm(up[3], up[2], 0x07060302u);
        cv.u[2] = __builtin_amdgcn_perm(up[5], up[4], 0x07060302u);
        cv.u[3] = __builtin_amdgcn_perm(up[7], up[6], 0x07060302u);
        return cv.s8;
    };

    #pragma unroll 2
    for (int cc = 0; cc < 32; cc += 2) {
        // ---- even half: chunk cc (set A) ----
        {
            const short8 afr = genE(a0A, a1A, cc);
            acc0 = __builtin_amdgcn_mfma_f32_16x16x32_bf16(afr, b0A, acc0, 0, 0, 0);
            acc1 = __builtin_amdgcn_mfma_f32_16x16x32_bf16(afr, b1A, acc1, 0, 0, 0);
            acc2 = __builtin_amdgcn_mfma_f32_16x16x32_bf16(afr, b2A, acc2, 0, 0, 0);
            acc3 = __builtin_amdgcn_mfma_f32_16x16x32_bf16(afr, b3A, acc3, 0, 0, 0);
            const int jn = (cc + 2 < 32) ? (cc + 2) * 32 : cc * 32;   // clamp tail
            a0A = *(const float4*)(aRow + jn);
            a1A = *(const float4*)(aRow + jn + 4);
            b0A = *(const short8*)(gB0 + jn);
            b1A = *(const short8*)(gB1 + jn);
            b2A = *(const short8*)(gB2 + jn);
            b3A = *(const short8*)(gB3 + jn);
        }
        // ---- odd half: chunk cc+1 (set B) ----
        {
            const short8 afr = genE(a0B, a1B, cc + 1);
            acc0 = __builtin_amdgcn_mfma_f32_16x16x32_bf16(afr, b0B, acc0, 0, 0, 0);
            acc1 = __builtin_amdgcn_mfma_f32_16x16x32_bf16(afr, b1B, acc1, 0, 0, 0);
            acc2 = __builtin_amdgcn_mfma_f32_16x16x32_bf16(afr, b2B, acc2, 0, 0, 0);
            acc3 = __builtin_amdgcn_mfma_f32_16x16x32_bf16(afr, b3B, acc3, 0, 0, 0);
            const int jn = (cc + 3 < 32) ? (cc + 3) * 32 : (cc + 1) * 32;
            a0B = *(const float4*)(aRow + jn);
            a1B = *(const float4*)(aRow + jn + 4);
            b0B = *(const short8*)(gB0 + jn);
            b1B = *(const short8*)(gB1 + jn);
            b2B = *(const short8*)(gB2 + jn);
            b3B = *(const short8*)(gB3 + jn);
        }
    }

    // den: reduce over the 4 q-lanes of each row
    dsum += __shfl_xor(dsum, 16, 64);
    dsum += __shfl_xor(dsum, 32, 64);

    // ---- epilogue: two-pass cross-group reduction in LDS, divide, store ----
    __syncthreads();
    float* red = (float*)sm;                 // [2][64][68]; col 64 holds den
    const int il = t >> 4, c4 = t & 15;
    float4 osum = {0.f, 0.f, 0.f, 0.f};
    float dtot = 0.f;
    #pragma unroll
    for (int pass = 0; pass < 2; ++pass) {
        if ((grp >> 1) == pass) {
            float* rp_ = red + (grp & 1) * 4352;
            #pragma unroll
            for (int nt = 0; nt < 4; ++nt) {
                floatx4 av = nt == 0 ? acc0 : nt == 1 ? acc1 : nt == 2 ? acc2 : acc3;
                #pragma unroll
                for (int rg = 0; rg < 4; ++rg)
                    rp_[(wsub * 16 + q * 4 + rg) * 68 + nt * 16 + m] = av[rg];
            }
            if (q == 0) rp_[(wsub * 16 + m) * 68 + 64] = dsum;
        }
        __syncthreads();
        {
            float4 v0 = *(const float4*)&red[il * 68 + c4 * 4];
            float4 v1 = *(const float4*)&red[4352 + il * 68 + c4 * 4];
            osum.x += v0.x + v1.x; osum.y += v0.y + v1.y;
            osum.z += v0.z + v1.z; osum.w += v0.w + v1.w;
            dtot += red[il * 68 + 64] + red[4352 + il * 68 + 64];
        }
        __syncthreads();
    }
    const float rinv = 1.0f / dtot;
    float4 o;
    o.x = osum.x * rinv; o.y = osum.y * rinv;
    o.z = osum.z * rinv; o.w = osum.w * rinv;
    *(float4*)(out + (((size_t)(b * NN + i0 + il)) << 6) + c4 * 4) = o;
}

extern "C" void kernel_launch(void* const* d_in, const int* in_sizes, int n_in,
                              void* d_out, int out_size, void* d_ws, size_t ws_size,
                              hipStream_t stream) {
    const float* X     = (const float*)d_in[0];
    const float* A     = (const float*)d_in[1];
    const float* W1    = (const float*)d_in[2];
    const float* W2    = (const float*)d_in[3];
    const float* alpha = (const float*)d_in[4];
    float* out = (float*)d_out;

    char* ws = (char*)d_ws;
    unsigned short* Gt = (unsigned short*)(ws);            // 2 MiB
    float* lvp   = (float*)(ws + 2097152);                 // 64 KiB
    float* rvp   = (float*)(ws + 2097152 + 65536);         // 64 KiB
    float* WcstG = (float*)(ws + 2097152 + 131072);        // 17408 B
    float* w1aG  = (float*)(ws + 2097152 + 131072 + 17408);// 512 B

    wc_kernel<<<1, 256, 0, stream>>>(W1, W2, alpha, WcstG, w1aG);
    prep_kernel<<<256, 256, 0, stream>>>(X, WcstG, w1aG, Gt, lvp, rvp);
    attn_kernel<<<256, 1024, 0, stream>>>(A, Gt, lvp, rvp, out);
}

// Round 5
// 160.463 us; speedup vs baseline: 1.2366x; 1.2366x over previous
//
#include <hip/hip_runtime.h>
#include <hip/hip_bf16.h>

typedef __attribute__((ext_vector_type(8))) short short8;
typedef __attribute__((ext_vector_type(4))) float floatx4;
typedef unsigned int u32;

#define NN 4096

static __device__ __forceinline__ unsigned f2bf_rne(float x) {
    union { float f; unsigned u; } v; v.f = x;
    unsigned r = v.u + 0x7fffu + ((v.u >> 16) & 1u);
    return r >> 16;
}
static __device__ __forceinline__ float bf2f(unsigned hi) {
    union { unsigned u; float f; } v; v.u = hi << 16; return v.f;
}

// ---- prep (fused wc, ROUND-0 PROVEN): per-block computes Wc=W1@W2, w1*alpha;
// then G = X@Wc (bf16 hi/lo MFMA) -> Gt bf16 [b*64+c][4096]; lv/rv fp32.
__global__ __launch_bounds__(256, 4)
void prep_kernel(const float* __restrict__ X,
                 const float* __restrict__ W1,
                 const float* __restrict__ W2,
                 const float* __restrict__ alpha,
                 unsigned short* __restrict__ Gt,
                 float* __restrict__ lv,
                 float* __restrict__ rv) {
    __shared__ __align__(16) char sm[53248];
    float* W1s  = (float*)sm;                 // [64][68]
    float* W2s  = (float*)(sm + 17408);       // [64][68]
    float* Wcst = (float*)(sm + 34816);       // Wc^T: [n][k] stride 68
    float* w1s  = (float*)(sm + 52224);       // [128]
    float* als  = (float*)(sm + 52736);       // [128]
    float* GsT  = (float*)sm;                 // epilogue reuse: [64][68]

    const int t = threadIdx.x;
    const int row0 = blockIdx.x * 64;         // flat b*N + n
    const int b = row0 >> 12, n0 = row0 & (NN - 1);
    const int w = t >> 6, lane = t & 63;
    const int m = lane & 15, q = lane >> 4;

    // issue X loads early (consumed much later)
    const int row = row0 + w * 16 + m;
    const float* xp = X + (size_t)row * 64;
    float4 x0 = *(const float4*)(xp + q * 8);
    float4 x1 = *(const float4*)(xp + q * 8 + 4);
    float4 x2 = *(const float4*)(xp + 32 + q * 8);
    float4 x3 = *(const float4*)(xp + 32 + q * 8 + 4);

    #pragma unroll
    for (int s = 0; s < 4; ++s) {
        int idx = s * 1024 + t * 4;
        int r = idx >> 6, cc = idx & 63;
        *(float4*)&W1s[r * 68 + cc] = *(const float4*)(W1 + idx);
        *(float4*)&W2s[r * 68 + cc] = *(const float4*)(W2 + idx);
    }
    if (t < 128) als[t] = alpha[t];
    __syncthreads();

    // Wc^T: thread (k = t>>2, nq = t&3) computes Wc[k][n], n in [nq*16, nq*16+16)
    {
        const int k = t >> 2, nq = t & 3;
        float acc[16];
        #pragma unroll
        for (int i = 0; i < 16; ++i) acc[i] = 0.f;
        for (int mm = 0; mm < 64; ++mm) {
            float w1v = W1s[k * 68 + mm];
            #pragma unroll
            for (int i = 0; i < 16; ++i)
                acc[i] += w1v * W2s[mm * 68 + nq * 16 + i];
        }
        #pragma unroll
        for (int i = 0; i < 16; ++i)
            Wcst[(nq * 16 + i) * 68 + k] = acc[i];
    }
    if (t < 64) {   // w1a = {W1@aL, W1@aR}
        float sl = 0.f, sr = 0.f;
        for (int cc2 = 0; cc2 < 64; ++cc2) {
            float wv = W1s[t * 68 + cc2];
            sl += wv * als[cc2];
            sr += wv * als[64 + cc2];
        }
        w1s[t] = sl; w1s[64 + t] = sr;
    }
    __syncthreads();

    const float xs[16] = {x0.x,x0.y,x0.z,x0.w, x1.x,x1.y,x1.z,x1.w,
                          x2.x,x2.y,x2.z,x2.w, x3.x,x3.y,x3.z,x3.w};

    // lv/rv fp32
    float pl = 0.f, pr = 0.f;
    #pragma unroll
    for (int ks = 0; ks < 2; ++ks)
        #pragma unroll
        for (int j = 0; j < 8; ++j) {
            int k = ks * 32 + q * 8 + j;
            float xv = xs[ks * 8 + j];
            pl += xv * w1s[k];
            pr += xv * w1s[64 + k];
        }
    pl += __shfl_xor(pl, 16, 64); pl += __shfl_xor(pl, 32, 64);
    pr += __shfl_xor(pr, 16, 64); pr += __shfl_xor(pr, 32, 64);
    if (q == 0) { lv[row] = pl; rv[row] = pr; }

    // bf16 hi/lo A-fragments
    short8 ah[2], al[2];
    #pragma unroll
    for (int ks = 0; ks < 2; ++ks)
        #pragma unroll
        for (int j = 0; j < 8; ++j) {
            float f = xs[ks * 8 + j];
            unsigned hb = f2bf_rne(f);
            float res = f - bf2f(hb);
            ah[ks][j] = (short)hb;
            al[ks][j] = (short)f2bf_rne(res);
        }

    // B-frags from Wcst
    short8 bfr[4][2];
    #pragma unroll
    for (int nt = 0; nt < 4; ++nt)
        #pragma unroll
        for (int ks = 0; ks < 2; ++ks) {
            const float* wp = &Wcst[(nt * 16 + m) * 68 + ks * 32 + q * 8];
            float4 w0 = *(const float4*)wp;
            float4 w1 = *(const float4*)(wp + 4);
            short8 bf;
            bf[0] = (short)f2bf_rne(w0.x); bf[1] = (short)f2bf_rne(w0.y);
            bf[2] = (short)f2bf_rne(w0.z); bf[3] = (short)f2bf_rne(w0.w);
            bf[4] = (short)f2bf_rne(w1.x); bf[5] = (short)f2bf_rne(w1.y);
            bf[6] = (short)f2bf_rne(w1.z); bf[7] = (short)f2bf_rne(w1.w);
            bfr[nt][ks] = bf;
        }

    floatx4 acc[4] = {{0,0,0,0},{0,0,0,0},{0,0,0,0},{0,0,0,0}};
    #pragma unroll
    for (int ks = 0; ks < 2; ++ks)
        #pragma unroll
        for (int nt = 0; nt < 4; ++nt) {
            acc[nt] = __builtin_amdgcn_mfma_f32_16x16x32_bf16(ah[ks], bfr[nt][ks], acc[nt], 0, 0, 0);
            acc[nt] = __builtin_amdgcn_mfma_f32_16x16x32_bf16(al[ks], bfr[nt][ks], acc[nt], 0, 0, 0);
        }

    __syncthreads();    // all Wcst/W1s reads done; sm@0 reused as GsT
    #pragma unroll
    for (int nt = 0; nt < 4; ++nt)
        #pragma unroll
        for (int rg = 0; rg < 4; ++rg)
            GsT[(nt * 16 + m) * 68 + w * 16 + q * 4 + rg] = acc[nt][rg];
    __syncthreads();
    unsigned* Gu = (unsigned*)Gt;
    #pragma unroll
    for (int it2 = 0; it2 < 8; ++it2) {
        int c2 = (t >> 5) + it2 * 8;
        int np = t & 31;
        unsigned lo = f2bf_rne(GsT[c2 * 68 + 2 * np]);
        unsigned hi = f2bf_rne(GsT[c2 * 68 + 2 * np + 1]);
        Gu[(((((size_t)(b * 64 + c2)) << 12) + n0) >> 1) + np] = lo | (hi << 16);
    }
}

// ---- attn_main v5: grid 1024 = (grp, i-tile, b), 256 thr = 4 waves.
// 4 independent blocks/CU -> 4 small barrier domains; when one block waits
// at its barrier, the other 3 blocks' waves run (round-0 had ONE 16-wave
// block/CU lockstepping on block-wide syncthreads).
// Proven pieces kept: G staged global->reg->ds_write into stride-40 LDS
// (round-0), double-buffered, ONE barrier/chunk; E computed in-register in
// consumer layout (v4); VALU dsum, no ones-MFMA (v4). Depth-2 reg prefetch
// for the G stage (sA/sB named sets) and A/rv rows (aA/aB).
// Output: f32 partials [blk][64 i][68] (col 64 = den) -> reduce kernel.
__global__ __launch_bounds__(256, 4)
void attn_main(const float* __restrict__ A,
               const unsigned short* __restrict__ Gt,
               const float* __restrict__ lv,
               const float* __restrict__ rv,
               float* __restrict__ pout) {
    __shared__ __align__(16) float rs[1024];                  // group's rv slice
    __shared__ __align__(16) unsigned short Gs[2][64 * 40];   // dbuf, stride 40

    const int bx = blockIdx.x;
    const int grp = bx & 3;
    const int it  = (bx >> 2) & 63;
    const int b   = bx >> 8;
    const int i0  = it * 64;
    const int t = threadIdx.x;
    const int wsub = t >> 6, lane = t & 63;
    const int m = lane & 15, q = lane >> 4;
    const int irow = wsub * 16 + m;

    // rs stage: rv[grp*1024 .. +1024)
    *(float4*)&rs[t * 4] = *(const float4*)(rv + (size_t)b * NN + grp * 1024 + t * 4);

    const float* aRow = A + (size_t)(i0 + irow) * NN + grp * 1024 + q * 8;
    // G stage: thread stages channel sc = t>>2, j-offset jj = (t&3)*8
    const int sc = t >> 2, jj = (t & 3) * 8;
    const unsigned short* gStage = Gt + (((size_t)(b * 64 + sc)) << 12) + grp * 1024 + jj;

    const float li = lv[b * NN + i0 + irow] * 1.44269504f;    // fold log2e
    const float li001 = li * 0.01f;

    // prologue: chunks 0,1,2 into s0/sA/sB; A chunks 0,1 into aA/aB
    short8 s0 = *(const short8*)(gStage);
    short8 sA = *(const short8*)(gStage + 32);
    short8 sB = *(const short8*)(gStage + 64);
    float4 a0A = *(const float4*)(aRow);
    float4 a1A = *(const float4*)(aRow + 4);
    float4 a0B = *(const float4*)(aRow + 32);
    float4 a1B = *(const float4*)(aRow + 36);

    const bool diag_grp = ((i0 >> 10) == grp);
    const int jd = (i0 + irow) - grp * 1024;

    floatx4 acc0 = {0,0,0,0}, acc1 = {0,0,0,0}, acc2 = {0,0,0,0}, acc3 = {0,0,0,0};
    float dsum = 0.f;

    *(short8*)&Gs[0][sc * 40 + jj] = s0;      // chunk 0 -> buf 0
    __syncthreads();                          // rs + buf0 ready

    auto genE = [&](float4 a0, float4 a1, int chunk) -> short8 {
        float aa[8] = {a0.x, a0.y, a0.z, a0.w, a1.x, a1.y, a1.z, a1.w};
        if (diag_grp && ((jd >> 5) == chunk)) {               // adj diag := 1
            const int dd = jd - (chunk * 32 + q * 8);
            #pragma unroll
            for (int e = 0; e < 8; ++e) if (dd == e) aa[e] = 1.0f;
        }
        const float4 r0 = *(const float4*)&rs[chunk * 32 + q * 8];
        const float4 r1 = *(const float4*)&rs[chunk * 32 + q * 8 + 4];
        const float rr[8] = {r0.x, r0.y, r0.z, r0.w, r1.x, r1.y, r1.z, r1.w};
        unsigned up[8];
        #pragma unroll
        for (int e = 0; e < 8; ++e) {
            float s = fmaxf(li * rr[e], li001 * rr[e]);       // leaky(li*r)
            float ev = __builtin_amdgcn_exp2f(s) * aa[e];
            unsigned u = __float_as_uint(ev) + 0x8000u;
            up[e] = u;
            dsum += __uint_as_float(u & 0xffff0000u);         // den = same bf16 vals
        }
        union { unsigned u[4]; short8 s8; } cv;
        cv.u[0] = __builtin_amdgcn_perm(up[1], up[0], 0x07060302u);
        cv.u[1] = __builtin_amdgcn_perm(up[3], up[2], 0x07060302u);
        cv.u[2] = __builtin_amdgcn_perm(up[5], up[4], 0x07060302u);
        cv.u[3] = __builtin_amdgcn_perm(up[7], up[6], 0x07060302u);
        return cv.s8;
    };

    for (int cc = 0; cc < 32; cc += 2) {
        // ---- even half: compute chunk cc (buf0); write cc+1; load cc+3 ----
        {
            *(short8*)&Gs[1][sc * 40 + jj] = sA;              // chunk cc+1 -> buf1
            { const int jn = (cc + 3 < 32) ? (cc + 3) * 32 : 0;
              sA = *(const short8*)(gStage + jn); }           // chunk cc+3
            const short8 afr = genE(a0A, a1A, cc);
            { const int jn = (cc + 2 < 32) ? (cc + 2) * 32 : 0;
              a0A = *(const float4*)(aRow + jn);
              a1A = *(const float4*)(aRow + jn + 4); }        // A chunk cc+2
            const short8 b0 = *(const short8*)&Gs[0][( m) * 40 + q * 8];
            const short8 b1 = *(const short8*)&Gs[0][(16 + m) * 40 + q * 8];
            const short8 b2 = *(const short8*)&Gs[0][(32 + m) * 40 + q * 8];
            const short8 b3 = *(const short8*)&Gs[0][(48 + m) * 40 + q * 8];
            acc0 = __builtin_amdgcn_mfma_f32_16x16x32_bf16(afr, b0, acc0, 0, 0, 0);
            acc1 = __builtin_amdgcn_mfma_f32_16x16x32_bf16(afr, b1, acc1, 0, 0, 0);
            acc2 = __builtin_amdgcn_mfma_f32_16x16x32_bf16(afr, b2, acc2, 0, 0, 0);
            acc3 = __builtin_amdgcn_mfma_f32_16x16x32_bf16(afr, b3, acc3, 0, 0, 0);
            __syncthreads();                                  // buf1 ready; buf0 reads done
        }
        // ---- odd half: compute chunk cc+1 (buf1); write cc+2; load cc+4 ----
        {
            *(short8*)&Gs[0][sc * 40 + jj] = sB;              // chunk cc+2 -> buf0
            { const int jn = (cc + 4 < 32) ? (cc + 4) * 32 : 0;
              sB = *(const short8*)(gStage + jn); }           // chunk cc+4
            const short8 afr = genE(a0B, a1B, cc + 1);
            { const int jn = (cc + 3 < 32) ? (cc + 3) * 32 : 0;
              a0B = *(const float4*)(aRow + jn);
              a1B = *(const float4*)(aRow + jn + 4); }        // A chunk cc+3
            const short8 b0 = *(const short8*)&Gs[1][( m) * 40 + q * 8];
            const short8 b1 = *(const short8*)&Gs[1][(16 + m) * 40 + q * 8];
            const short8 b2 = *(const short8*)&Gs[1][(32 + m) * 40 + q * 8];
            const short8 b3 = *(const short8*)&Gs[1][(48 + m) * 40 + q * 8];
            acc0 = __builtin_amdgcn_mfma_f32_16x16x32_bf16(afr, b0, acc0, 0, 0, 0);
            acc1 = __builtin_amdgcn_mfma_f32_16x16x32_bf16(afr, b1, acc1, 0, 0, 0);
            acc2 = __builtin_amdgcn_mfma_f32_16x16x32_bf16(afr, b2, acc2, 0, 0, 0);
            acc3 = __builtin_amdgcn_mfma_f32_16x16x32_bf16(afr, b3, acc3, 0, 0, 0);
            __syncthreads();                                  // buf0 ready; buf1 reads done
        }
    }

    // den: reduce over the 4 q-lanes of each row
    dsum += __shfl_xor(dsum, 16, 64);
    dsum += __shfl_xor(dsum, 32, 64);

    // ---- epilogue: direct f32 partial store, no LDS, no barriers ----
    float* pb = pout + (size_t)bx * (64 * 68);
    #pragma unroll
    for (int nt = 0; nt < 4; ++nt) {
        floatx4 av = nt == 0 ? acc0 : nt == 1 ? acc1 : nt == 2 ? acc2 : acc3;
        #pragma unroll
        for (int rg = 0; rg < 4; ++rg)
            pb[(wsub * 16 + q * 4 + rg) * 68 + nt * 16 + m] = av[rg];
    }
    if (q == 0) pb[(wsub * 16 + m) * 68 + 64] = dsum;
}

// ---- attn_reduce: grid 256 = (i-tile, b), 256 thr. Sums the 4 grp
// partials, divides by summed den, writes out.
__global__ __launch_bounds__(256, 4)
void attn_reduce(const float* __restrict__ pout,
                 float* __restrict__ out) {
    const int bx = blockIdx.x;
    const int it = bx & 63, b = bx >> 6;
    const int t = threadIdx.x;
    const int row = t >> 2, quad = t & 3;

    const float* base = pout + (size_t)((b * 64 + it) * 4) * (64 * 68);
    float den = 0.f;
    #pragma unroll
    for (int p = 0; p < 4; ++p)
        den += base[p * 4352 + row * 68 + 64];
    const float rinv = 1.0f / den;

    float* op = out + (((size_t)(b * NN + it * 64 + row)) << 6) + quad * 16;
    #pragma unroll
    for (int f = 0; f < 4; ++f) {
        float4 s = {0.f, 0.f, 0.f, 0.f};
        #pragma unroll
        for (int p = 0; p < 4; ++p) {
            const float4 v = *(const float4*)&base[p * 4352 + row * 68 + quad * 16 + f * 4];
            s.x += v.x; s.y += v.y; s.z += v.z; s.w += v.w;
        }
        float4 o;
        o.x = s.x * rinv; o.y = s.y * rinv; o.z = s.z * rinv; o.w = s.w * rinv;
        *(float4*)(op + f * 4) = o;
    }
}

extern "C" void kernel_launch(void* const* d_in, const int* in_sizes, int n_in,
                              void* d_out, int out_size, void* d_ws, size_t ws_size,
                              hipStream_t stream) {
    const float* X     = (const float*)d_in[0];
    const float* A     = (const float*)d_in[1];
    const float* W1    = (const float*)d_in[2];
    const float* W2    = (const float*)d_in[3];
    const float* alpha = (const float*)d_in[4];
    float* out = (float*)d_out;

    char* ws = (char*)d_ws;
    unsigned short* Gt = (unsigned short*)(ws);            // 2 MiB
    float* lvp  = (float*)(ws + 2097152);                  // 64 KiB
    float* rvp  = (float*)(ws + 2097152 + 65536);          // 64 KiB
    float* pout = (float*)(ws + 2097152 + 131072);         // 1024*4352*4 = 17.8 MiB

    prep_kernel<<<256, 256, 0, stream>>>(X, W1, W2, alpha, Gt, lvp, rvp);
    attn_main<<<1024, 256, 0, stream>>>(A, Gt, lvp, rvp, pout);
    attn_reduce<<<256, 256, 0, stream>>>(pout, out);
}